// Round 3
// baseline (229.669 us; speedup 1.0000x reference)
//
#include <hip/hip_runtime.h>
#include <math.h>

#define N_ 4
#define C_ 64
#define H_ 128
#define W_ 128
#define HW_ (H_ * W_)
#define K2_ 9
#define COUT 64
#define CK 576          // C_*K2_
#define TP 16           // pixels per block

typedef __bf16 bf16x8 __attribute__((ext_vector_type(8)));
typedef float floatx4 __attribute__((ext_vector_type(4)));
typedef float floatx8 __attribute__((ext_vector_type(8)));

// A-rows (fp32, converted in-register) x B (bf16 LDS, XOR-swizzled) -> 16x16 tile
__device__ __forceinline__ floatx4 gemm_tile(const float* __restrict__ arow,
                                             const __bf16* __restrict__ browbase,
                                             int q, int colm7) {
    floatx4 acc = {0.f, 0.f, 0.f, 0.f};
#pragma unroll 3
    for (int it = 0; it < 18; ++it) {
        const float* ap = arow + 32 * it + q * 8;
        bf16x8 a = __builtin_convertvector(*(const floatx8*)ap, bf16x8);
        unsigned jc = ((unsigned)(q + 4 * it)) ^ (unsigned)colm7;
        bf16x8 bb = *(const bf16x8*)(browbase + jc * 8);
        acc = __builtin_amdgcn_mfma_f32_16x16x32_bf16(a, bb, acc, 0, 0, 0);
    }
    return acc;
}

__global__ __launch_bounds__(256) void fused_kernel(const float* __restrict__ x,
                                                    const float* __restrict__ w_off,
                                                    const float* __restrict__ b_off,
                                                    const float* __restrict__ w,
                                                    const float* __restrict__ b,
                                                    float* __restrict__ out) {
    __shared__ __align__(16) __bf16 s_x[TP * CK];   // [p][ck], 16B chunks XOR-swizzled by p&7
    __shared__ float s_om[32 * TP];                  // offset-conv out [co][p]
    __shared__ floatx4 s_w4[K2_ * TP];               // per-(k,p) 4 position-weights (mask folded)
    __shared__ unsigned short s_boff[K2_ * TP];      // per-(k,p) clamped base element offset

    int t = threadIdx.x;
    int pixbase = blockIdx.x * TP;                   // over N*H*W
    int wo0 = pixbase & (W_ - 1);
    int ho  = (pixbase >> 7) & (H_ - 1);
    int n   = pixbase >> 14;
    const float* xn = x + (size_t)n * C_ * HW_;

    int p = t & 15;            // pixel
    int s = t >> 4;            // 0..15
    int pm7 = p & 7;
    unsigned basep = (unsigned)p * CK;

    // ---- Phase A: integer-tap im2col (zero-padded) -> s_x bf16, swizzled ----
#pragma unroll
    for (int k = 0; k < 9; ++k) {
        int kh = k / 3, kw = k - kh * 3;
        int y  = ho - 1 + kh;
        int xx = wo0 + p - 1 + kw;
        bool valid = ((unsigned)y < (unsigned)H_) && ((unsigned)xx < (unsigned)W_);
        int yc = min(max(y, 0), H_ - 1);
        int xc = min(max(xx, 0), W_ - 1);
        unsigned boff = (unsigned)(yc * W_ + xc);
#pragma unroll
        for (int cc = 0; cc < 4; ++cc) {
            int c = cc * 16 + s;
            float v = xn[(unsigned)c * HW_ + boff];
            v = valid ? v : 0.f;
            int ck = c * 9 + k;
            unsigned idx = basep + ((((unsigned)ck >> 3) ^ pm7) << 3) + (ck & 7);
            s_x[idx] = (__bf16)v;
        }
    }
    __syncthreads();

    int lane = t & 63;
    int wv   = t >> 6;
    int q    = lane >> 4;
    int col  = lane & 15;
    const __bf16* brow = s_x + col * CK;
    int colm7 = col & 7;

    // ---- Phase B: offset conv via MFMA (waves 0,1; rows>=27 produce unused garbage) ----
    if (wv < 2) {
        int row = min(16 * wv + col, 26);           // clamp keeps loads in-bounds
        floatx4 acc = gemm_tile(w_off + (size_t)row * CK, brow, q, colm7);
#pragma unroll
        for (int r = 0; r < 4; ++r)
            s_om[(16 * wv + q * 4 + r) * TP + col] = acc[r];
    }
    __syncthreads();

    // ---- coords: bilinear position-weights + clamped base offset (144 threads) ----
    if (t < K2_ * TP) {
        int k  = t >> 4;
        int pp = t & 15;
        float dy = s_om[(2 * k) * TP + pp]     + b_off[2 * k];
        float dx = s_om[(2 * k + 1) * TP + pp] + b_off[2 * k + 1];
        float mm = s_om[(18 + k) * TP + pp]    + b_off[18 + k];
        float msk = 1.f / (1.f + expf(-mm));
        int kh = k / 3, kw = k - kh * 3;
        float py = (float)(ho - 1 + kh) + dy;
        float px = (float)(wo0 + pp - 1 + kw) + dx;
        float yf = floorf(py), xf = floorf(px);
        float fy = py - yf, fx = px - xf;
        int y0 = (int)yf, x0 = (int)xf;
        float wy0 = ((unsigned)y0 < (unsigned)H_)       ? 1.f - fy : 0.f;
        float wy1 = ((unsigned)(y0 + 1) < (unsigned)H_) ? fy       : 0.f;
        float wx0 = ((unsigned)x0 < (unsigned)W_)       ? 1.f - fx : 0.f;
        float wx1 = ((unsigned)(x0 + 1) < (unsigned)W_) ? fx       : 0.f;
        int y0c = min(max(y0, 0), H_ - 2);
        int x0c = min(max(x0, 0), W_ - 2);
        // shift weights onto the clamped positions (OOB-safe addresses, exact zeros)
        float t0 = (y0 == y0c) ? wy0 : ((y0 + 1 == y0c) ? wy1 : 0.f);
        float t1 = (y0 == y0c) ? wy1 : ((y0 == y0c + 1) ? wy0 : 0.f);
        float u0 = (x0 == x0c) ? wx0 : ((x0 + 1 == x0c) ? wx1 : 0.f);
        float u1 = (x0 == x0c) ? wx1 : ((x0 == x0c + 1) ? wx0 : 0.f);
        floatx4 w4 = { t0 * u0 * msk, t0 * u1 * msk, t1 * u0 * msk, t1 * u1 * msk };
        s_w4[t] = w4;
        s_boff[t] = (unsigned short)(y0c * W_ + x0c);
    }
    __syncthreads();

    // ---- Phase C: bilinear sample * mask -> s_x (overwrite, swizzled bf16) ----
    for (int k = 0; k < 9; ++k) {
        floatx4 w4 = s_w4[k * 16 + p];
        unsigned boff = s_boff[k * 16 + p];
#pragma unroll
        for (int cc = 0; cc < 4; ++cc) {
            int c = cc * 16 + s;
            const float* xp = xn + (unsigned)c * HW_ + boff;
            float v = w4[0] * xp[0] + w4[1] * xp[1] + w4[2] * xp[W_] + w4[3] * xp[W_ + 1];
            int ck = c * 9 + k;
            unsigned idx = basep + ((((unsigned)ck >> 3) ^ pm7) << 3) + (ck & 7);
            s_x[idx] = (__bf16)v;
        }
    }
    __syncthreads();

    // ---- Phase D: main conv MFMA (4 waves) + bias + relu ----
    {
        int row = 16 * wv + col;                    // output channel within A
        floatx4 acc = gemm_tile(w + (size_t)row * CK, brow, q, colm7);
#pragma unroll
        for (int r = 0; r < 4; ++r) {
            int o = 16 * wv + q * 4 + r;
            float v = acc[r] + b[o];
            out[(((size_t)n * COUT + o) * H_ + ho) * W_ + wo0 + col] = fmaxf(v, 0.f);
        }
    }
}

extern "C" void kernel_launch(void* const* d_in, const int* in_sizes, int n_in,
                              void* d_out, int out_size, void* d_ws, size_t ws_size,
                              hipStream_t stream) {
    const float* x     = (const float*)d_in[0];
    const float* w_off = (const float*)d_in[1];
    const float* b_off = (const float*)d_in[2];
    const float* w     = (const float*)d_in[3];
    const float* b     = (const float*)d_in[4];
    float* out = (float*)d_out;

    int nblocks = N_ * H_ * W_ / TP;   // 4096
    fused_kernel<<<nblocks, 256, 0, stream>>>(x, w_off, b_off, w, b, out);
}